// Round 1
// baseline (566.962 us; speedup 1.0000x reference)
//
#include <hip/hip_runtime.h>
#include <stdint.h>
#include <initializer_list>

// Keep every f32 op un-fused: the reference (numpy/jax f32) computes
// inter = ih*iw; union = a_i + a_j - inter as separate rounded ops. With
// HIP's default -ffp-contract=fast the subtract would fuse into an FMA and
// could flip borderline iou > 0.5 decisions -> wrong box selected.
#pragma clang fp contract(off)

namespace {
constexpr int kN = 21824;      // 128^2 + 64^2 + 32^2 + 16^2 + 8^2
constexpr int kB = 16;
constexpr int kC = 80;
constexpr int kK = 256;        // K_CAND
constexpr int kMaxPC = 100;
constexpr int kMaxDet = 100;
}

// ---- 48-bit sort key: score bits (high 32) | (0xFFFF - index) (low 16) ----
// scores are >= 0 so the raw f32 bit pattern is order-monotone; the index
// complement reproduces jax top_k's stable tie-break (lower index wins).
__device__ __forceinline__ uint64_t make_key(float s, int n) {
  return ((uint64_t)__float_as_uint(s) << 16) | (uint32_t)(0xFFFF - n);
}

// Block-wide (256 threads) inclusive prefix scan.
__device__ uint32_t block_scan_incl(uint32_t val) {
  __shared__ uint32_t wsum[4];
  int lane = threadIdx.x & 63;
  int wave = threadIdx.x >> 6;
  for (int d = 1; d < 64; d <<= 1) {
    uint32_t t = __shfl_up(val, (unsigned)d, 64);
    if (lane >= d) val += t;
  }
  if (lane == 63) wsum[wave] = val;
  __syncthreads();
  uint32_t off = 0;
  for (int w = 0; w < wave; ++w) off += wsum[w];
  __syncthreads();
  return val + off;
}

// Exact top-K threshold: returns the full 48-bit key of the K-th largest
// element of s[0..count). Keys are unique, so gathering key >= result yields
// exactly K elements. 6 radix passes of 8 bits, data stays L2-resident.
__device__ uint64_t radix_select(const float* __restrict__ s, int count, int K) {
  __shared__ uint32_t hist[256];
  __shared__ int sel_d;
  __shared__ uint32_t sel_k;
  int tid = threadIdx.x;
  uint64_t prefix = 0;
  uint32_t krem = (uint32_t)K;
  for (int shift = 40; shift >= 0; shift -= 8) {
    hist[tid] = 0;
    __syncthreads();
    uint64_t pmask = (shift == 40) ? 0ull : (~0ull << (shift + 8));
    for (int n = tid; n < count; n += 256) {
      uint64_t k = make_key(s[n], n);
      if ((k & pmask) == prefix)
        atomicAdd(&hist[(uint32_t)(k >> shift) & 0xFFu], 1u);
    }
    __syncthreads();
    uint32_t v = hist[255 - tid];
    uint32_t S = block_scan_incl(v);           // = sum of hist[255-tid .. 255]
    if (S >= krem && (S - v) < krem) {         // unique crossing thread
      sel_d = 255 - tid;
      sel_k = krem - (S - v);
    }
    __syncthreads();
    prefix |= ((uint64_t)sel_d) << shift;
    krem = sel_k;
    __syncthreads();
  }
  return prefix;
}

// ---- decode boxes: (B,N,4) regs -> (B,N,4) [y1,x1,y2,x2] scaled ----
__global__ __launch_bounds__(256) void decode_boxes_kernel(
    const float* __restrict__ regs, float* __restrict__ boxes) {
  int i = blockIdx.x * 256 + threadIdx.x;
  if (i >= kB * kN) return;
  int n = i % kN;
  int off, hl;
  float sf;
  if (n < 16384)      { off = 0;     hl = 7; sf = 8.f;   }
  else if (n < 20480) { off = 16384; hl = 6; sf = 16.f;  }
  else if (n < 21504) { off = 20480; hl = 5; sf = 32.f;  }
  else if (n < 21760) { off = 21504; hl = 4; sf = 64.f;  }
  else                { off = 21760; hl = 3; sf = 128.f; }
  int k = n - off;
  // meshgrid(h, w) with 'xy' indexing -> gy = k % H, gx = k / H
  float gx = (float)(k >> hl);
  float gy = (float)(k & ((1 << hl) - 1));
  const float4 r = ((const float4*)regs)[i];
  float4 o;
  o.x = (gy - r.z) * sf;  // y1
  o.y = (gx - r.x) * sf;  // x1
  o.z = (gy + r.w) * sf;  // y2
  o.w = (gx + r.y) * sf;  // x2
  ((float4*)boxes)[i] = o;
}

// ---- fused score (clf*ctr) + transpose (b,N,C) -> (lb,C,N) ----
__global__ __launch_bounds__(256) void score_transpose_kernel(
    const float* __restrict__ clfs, const float* __restrict__ ctrs,
    float* __restrict__ scores_t, int b0) {
  __shared__ float tile[32][81];   // +1 pad: conflict-free column reads
  __shared__ float ctile[32];
  int lb = blockIdx.y;             // local batch within chunk
  int b = lb + b0;
  int n0 = blockIdx.x * 32;
  int tid = threadIdx.x;
  if (tid < 32) ctile[tid] = ctrs[(size_t)b * kN + n0 + tid];
  const float* src = clfs + ((size_t)b * kN + n0) * kC;
  for (int e = tid; e < 32 * kC; e += 256)
    tile[e / kC][e % kC] = src[e];       // coalesced global read
  __syncthreads();
  for (int e = tid; e < 32 * kC; e += 256) {
    int c = e >> 5;
    int nl = e & 31;
    scores_t[((size_t)(lb * kC + c)) * kN + n0 + nl] = tile[nl][c] * ctile[nl];
  }
}

// ---- per-(batch,class): top-256 -> greedy NMS -> stable top-100 ----
__global__ __launch_bounds__(256) void nms_class_kernel(
    const float* __restrict__ scores_t, const float* __restrict__ boxes,
    float* __restrict__ cls_boxes, float* __restrict__ cls_scores, int b0) {
  int lb = blockIdx.x / kC;
  int c = blockIdx.x % kC;
  int b = lb + b0;
  int tid = threadIdx.x;
  const float* s = scores_t + ((size_t)(lb * kC + c)) * kN;

  uint64_t thr = radix_select(s, kN, kK);

  __shared__ uint32_t cnt;
  __shared__ uint64_t gkey[kK];
  if (tid == 0) cnt = 0;
  __syncthreads();
  for (int n = tid; n < kN; n += 256) {
    uint64_t k = make_key(s[n], n);
    if (k >= thr) gkey[atomicAdd(&cnt, 1u)] = k;   // exactly kK land here
  }
  __syncthreads();

  // stable sort by rank-counting (keys unique -> rank is a permutation)
  uint64_t myk = gkey[tid];
  int rank = 0;
  for (int i = 0; i < kK; ++i) rank += (gkey[i] > myk);

  __shared__ float by1[kK], bx1[kK], by2[kK], bx2[kK], barea[kK], bsc[kK];
  __shared__ int keep[kK];
  int n = 0xFFFF - (int)(myk & 0xFFFF);
  float sc_v = __uint_as_float((uint32_t)(myk >> 16));
  const float* bp = boxes + ((size_t)b * kN + n) * 4;
  float y1 = bp[0], x1 = bp[1], y2 = bp[2], x2 = bp[3];
  by1[rank] = y1; bx1[rank] = x1; by2[rank] = y2; bx2[rank] = x2;
  barea[rank] = (y2 - y1) * (x2 - x1);
  bsc[rank] = sc_v;
  keep[rank] = (sc_v > 0.05f) ? 1 : 0;   // valid = top_s > CONF_THR
  __syncthreads();

  // greedy NMS, exact reference op order (contract(off) is active)
  float my_y1 = by1[tid], my_x1 = bx1[tid], my_y2 = by2[tid], my_x2 = bx2[tid];
  float my_a = barea[tid];
  for (int i = 0; i < kK; ++i) {
    if (keep[i]) {                       // uniform across block
      if (tid > i && keep[tid]) {
        float yy1 = fmaxf(by1[i], my_y1);
        float yy2 = fminf(by2[i], my_y2);
        float xx1 = fmaxf(bx1[i], my_x1);
        float xx2 = fminf(bx2[i], my_x2);
        float ih = fmaxf(yy2 - yy1, 0.0f);
        float iw = fmaxf(xx2 - xx1, 0.0f);
        float inter = ih * iw;
        float un = barea[i] + my_a - inter;
        float iou = inter / fmaxf(un, 1e-8f);
        if (iou > 0.5f) keep[tid] = 0;
      }
    }
    __syncthreads();
  }

  // stable top-100 of kept scores (zeros tie-break by candidate position)
  float ks = keep[tid] ? bsc[tid] : 0.0f;
  uint64_t k2 = ((uint64_t)__float_as_uint(ks) << 16) | (uint32_t)(0xFFFF - tid);
  gkey[tid] = k2;
  __syncthreads();
  int rank2 = 0;
  for (int i = 0; i < kK; ++i) rank2 += (gkey[i] > k2);
  if (rank2 < kMaxPC) {
    size_t obase = ((size_t)(b * kC + c)) * kMaxPC + rank2;
    cls_scores[obase] = ks;
    float* ob = cls_boxes + obase * 4;
    ob[0] = by1[tid]; ob[1] = bx1[tid]; ob[2] = by2[tid]; ob[3] = bx2[tid];
  }
}

// ---- per-batch: stable top-100 over 80*100 entries, write final outputs ----
__global__ __launch_bounds__(256) void final_topk_kernel(
    const float* __restrict__ cls_scores, const float* __restrict__ cls_boxes,
    float* __restrict__ out) {
  int b = blockIdx.x;
  int tid = threadIdx.x;
  const int M = kC * kMaxPC;  // 8000
  const float* s = cls_scores + (size_t)b * M;

  uint64_t thr = radix_select(s, M, kMaxDet);

  __shared__ uint32_t cnt;
  __shared__ uint64_t gkey[kMaxDet];
  if (tid == 0) cnt = 0;
  __syncthreads();
  for (int f = tid; f < M; f += 256) {
    uint64_t k = make_key(s[f], f);
    if (k >= thr) gkey[atomicAdd(&cnt, 1u)] = k;
  }
  __syncthreads();

  if (tid < kMaxDet) {
    uint64_t myk = gkey[tid];
    int rank = 0;
    for (int i = 0; i < kMaxDet; ++i) rank += (gkey[i] > myk);
    float sv = __uint_as_float((uint32_t)(myk >> 16));
    int f = 0xFFFF - (int)(myk & 0xFFFF);
    int cls = f / 100;
    const float* bp = cls_boxes + ((size_t)b * M + f) * 4;
    float m = (sv > 0.0f) ? 1.0f : 0.0f;   // fin_b zeroed where fin_s <= 0
    float* ob = out + ((size_t)b * kMaxDet + rank) * 4;
    ob[0] = bp[0] * m; ob[1] = bp[1] * m; ob[2] = bp[2] * m; ob[3] = bp[3] * m;
    out[(size_t)kB * kMaxDet * 4 + (size_t)b * kMaxDet + rank] = (float)cls;
    out[(size_t)kB * kMaxDet * 5 + (size_t)b * kMaxDet + rank] = sv;
  }
}

extern "C" void kernel_launch(void* const* d_in, const int* in_sizes, int n_in,
                              void* d_out, int out_size, void* d_ws, size_t ws_size,
                              hipStream_t stream) {
  (void)in_sizes; (void)n_in; (void)out_size;
  const float* regs = (const float*)d_in[0];
  const float* ctrs = (const float*)d_in[1];
  const float* clfs = (const float*)d_in[2];
  float* out = (float*)d_out;

  const size_t boxesB  = (size_t)kB * kN * 4 * sizeof(float);          // 5.6 MB
  const size_t clsBoxB = (size_t)kB * kC * kMaxPC * 4 * sizeof(float); // 2.0 MB
  const size_t clsScB  = (size_t)kB * kC * kMaxPC * sizeof(float);     // 0.5 MB
  const size_t fixed = boxesB + clsBoxB + clsScB;

  // scores_t needs cb*80*N*4 bytes; chunk batches if ws is small.
  int cb = 0;
  for (int t : {16, 8, 4, 2, 1}) {
    if (ws_size >= fixed + (size_t)t * kC * kN * sizeof(float)) { cb = t; break; }
  }
  if (cb == 0) return;  // workspace too small -- fail visibly, no OOB writes

  char* p = (char*)d_ws;
  float* boxes      = (float*)p; p += boxesB;
  float* cls_boxes  = (float*)p; p += clsBoxB;
  float* cls_scores = (float*)p; p += clsScB;
  float* scores_t   = (float*)p;

  decode_boxes_kernel<<<(kB * kN + 255) / 256, 256, 0, stream>>>(regs, boxes);
  for (int b0 = 0; b0 < kB; b0 += cb) {
    score_transpose_kernel<<<dim3(kN / 32, cb), 256, 0, stream>>>(clfs, ctrs, scores_t, b0);
    nms_class_kernel<<<cb * kC, 256, 0, stream>>>(scores_t, boxes, cls_boxes, cls_scores, b0);
  }
  final_topk_kernel<<<kB, 256, 0, stream>>>(cls_scores, cls_boxes, out);
}

// Round 2
// 423.077 us; speedup vs baseline: 1.3401x; 1.3401x over previous
//
#include <hip/hip_runtime.h>
#include <stdint.h>
#include <initializer_list>

// Keep every f32 op un-fused: the reference (numpy/jax f32) computes
// inter = ih*iw; union = a_i + a_j - inter as separate rounded ops. With
// HIP's default -ffp-contract=fast the subtract would fuse into an FMA and
// could flip borderline iou > 0.5 decisions -> wrong box selected.
#pragma clang fp contract(off)

namespace {
constexpr int kN = 21824;      // 128^2 + 64^2 + 32^2 + 16^2 + 8^2
constexpr int kB = 16;
constexpr int kC = 80;
constexpr int kK = 256;        // K_CAND
constexpr int kMaxPC = 100;
constexpr int kMaxDet = 100;
constexpr int kBins1 = 2048;   // first-pass histogram bins (top 11 score bits)
constexpr int kCap = 1536;     // LDS candidate capacity (u64 keys)
}

// ---- 48-bit sort key: score bits (high 32) | (0xFFFF - index) (low 16) ----
// scores are >= 0 so the raw f32 bit pattern is order-monotone; the index
// complement reproduces jax top_k's stable tie-break (lower index wins).
__device__ __forceinline__ uint64_t make_key(float s, int n) {
  return ((uint64_t)__float_as_uint(s) << 16) | (uint32_t)(0xFFFF - n);
}

// Block-wide (256 threads) inclusive prefix scan.
__device__ uint32_t block_scan_incl(uint32_t val) {
  __shared__ uint32_t wsum[4];
  int lane = threadIdx.x & 63;
  int wave = threadIdx.x >> 6;
  for (int d = 1; d < 64; d <<= 1) {
    uint32_t t = __shfl_up(val, (unsigned)d, 64);
    if (lane >= d) val += t;
  }
  if (lane == 63) wsum[wave] = val;
  __syncthreads();
  uint32_t off = 0;
  for (int w = 0; w < wave; ++w) off += wsum[w];
  __syncthreads();
  return val + off;
}

// Exact top-K threshold over count elements (used only for the tiny final
// top-100 over 8000): returns the full 48-bit key of the K-th largest.
__device__ uint64_t radix_select(const float* __restrict__ s, int count, int K) {
  __shared__ uint32_t hist[256];
  __shared__ int sel_d;
  __shared__ uint32_t sel_k;
  int tid = threadIdx.x;
  uint64_t prefix = 0;
  uint32_t krem = (uint32_t)K;
  for (int shift = 40; shift >= 0; shift -= 8) {
    hist[tid] = 0;
    __syncthreads();
    uint64_t pmask = (shift == 40) ? 0ull : (~0ull << (shift + 8));
    for (int n = tid; n < count; n += 256) {
      uint64_t k = make_key(s[n], n);
      if ((k & pmask) == prefix)
        atomicAdd(&hist[(uint32_t)(k >> shift) & 0xFFu], 1u);
    }
    __syncthreads();
    uint32_t v = hist[255 - tid];
    uint32_t S = block_scan_incl(v);
    if (S >= krem && (S - v) < krem) {
      sel_d = 255 - tid;
      sel_k = krem - (S - v);
    }
    __syncthreads();
    prefix |= ((uint64_t)sel_d) << shift;
    krem = sel_k;
    __syncthreads();
  }
  return prefix;
}

// ---- decode boxes: (B,N,4) regs -> (B,N,4) [y1,x1,y2,x2] scaled ----
__global__ __launch_bounds__(256) void decode_boxes_kernel(
    const float* __restrict__ regs, float* __restrict__ boxes) {
  int i = blockIdx.x * 256 + threadIdx.x;
  if (i >= kB * kN) return;
  int n = i % kN;
  int off, hl;
  float sf;
  if (n < 16384)      { off = 0;     hl = 7; sf = 8.f;   }
  else if (n < 20480) { off = 16384; hl = 6; sf = 16.f;  }
  else if (n < 21504) { off = 20480; hl = 5; sf = 32.f;  }
  else if (n < 21760) { off = 21504; hl = 4; sf = 64.f;  }
  else                { off = 21760; hl = 3; sf = 128.f; }
  int k = n - off;
  // meshgrid(h, w) with 'xy' indexing -> gy = k % H, gx = k / H
  float gx = (float)(k >> hl);
  float gy = (float)(k & ((1 << hl) - 1));
  const float4 r = ((const float4*)regs)[i];
  float4 o;
  o.x = (gy - r.z) * sf;  // y1
  o.y = (gx - r.x) * sf;  // x1
  o.z = (gy + r.w) * sf;  // y2
  o.w = (gx + r.y) * sf;  // x2
  ((float4*)boxes)[i] = o;
}

// ---- fused score (clf*ctr) + transpose (b,N,C) -> (lb,C,N) ----
__global__ __launch_bounds__(256) void score_transpose_kernel(
    const float* __restrict__ clfs, const float* __restrict__ ctrs,
    float* __restrict__ scores_t, int b0) {
  __shared__ float tile[32][81];   // +1 pad: conflict-free column reads
  __shared__ float ctile[32];
  int lb = blockIdx.y;             // local batch within chunk
  int b = lb + b0;
  int n0 = blockIdx.x * 32;
  int tid = threadIdx.x;
  if (tid < 32) ctile[tid] = ctrs[(size_t)b * kN + n0 + tid];
  const float4* src = (const float4*)(clfs + ((size_t)b * kN + n0) * kC);
  for (int e = tid; e < 32 * kC / 4; e += 256) {
    float4 v = src[e];
    int base = e * 4;
    tile[base / kC][base % kC] = v.x;       // kC=80: elements of one float4
    tile[(base + 1) / kC][(base + 1) % kC] = v.y;
    tile[(base + 2) / kC][(base + 2) % kC] = v.z;
    tile[(base + 3) / kC][(base + 3) % kC] = v.w;
  }
  __syncthreads();
  for (int e = tid; e < 32 * kC; e += 256) {
    int c = e >> 5;
    int nl = e & 31;
    scores_t[((size_t)(lb * kC + c)) * kN + n0 + nl] = tile[nl][c] * ctile[nl];
  }
}

// ---- per-(batch,class): 2-pass exact top-256 -> greedy NMS -> top-100 ----
__global__ __launch_bounds__(256) void nms_class_kernel(
    const float* __restrict__ scores_t, const float* __restrict__ boxes,
    float* __restrict__ cls_boxes, float* __restrict__ cls_scores, int b0) {
  int lb = blockIdx.x / kC;
  int c = blockIdx.x % kC;
  int b = lb + b0;
  int tid = threadIdx.x;
  const float* s = scores_t + ((size_t)(lb * kC + c)) * kN;
  const float4* s4 = (const float4*)s;     // rows are 16B-aligned (kN*4 % 16 == 0)
  constexpr int kN4 = kN / 4;              // 5456, exact

  __shared__ uint32_t hist[kBins1];        // 8 KB (refine passes reuse low bins)
  __shared__ uint64_t keybuf[kCap];        // 12 KB
  __shared__ uint64_t skey[kK];            // 2 KB, sorted top-256 keys
  __shared__ int sel_bin;
  __shared__ uint32_t sel_hd, sel_above;
  __shared__ uint32_t cnt;

  // ---- pass 1: 2048-bin histogram over key bits [37..48) = score bits >> 21
  for (int i = tid; i < kBins1; i += 256) hist[i] = 0;
  __syncthreads();
  for (int i = tid; i < kN4; i += 256) {
    float4 f = s4[i];
    atomicAdd(&hist[__float_as_uint(f.x) >> 21], 1u);
    atomicAdd(&hist[__float_as_uint(f.y) >> 21], 1u);
    atomicAdd(&hist[__float_as_uint(f.z) >> 21], 1u);
    atomicAdd(&hist[__float_as_uint(f.w) >> 21], 1u);
  }
  __syncthreads();
  // descending scan: thread t covers bins [2047-8t .. 2040-8t]
  uint32_t krem = kK;
  {
    uint32_t bl[8], v = 0;
    int base = kBins1 - 1 - 8 * tid;
    for (int j = 0; j < 8; ++j) { bl[j] = hist[base - j]; v += bl[j]; }
    uint32_t S = block_scan_incl(v);
    if (S >= krem && (S - v) < krem) {
      uint32_t cum = S - v;
      for (int j = 0; j < 8; ++j) {
        cum += bl[j];
        if (cum >= krem) { sel_bin = base - j; sel_hd = bl[j]; sel_above = cum - bl[j]; break; }
      }
    }
    __syncthreads();
  }
  uint64_t prefix = (uint64_t)sel_bin;
  krem = kK - sel_above;
  uint32_t Sge = (kK - krem) + sel_hd;     // candidates if we gather >= prefix floor
  int shift = 37;
  __syncthreads();

  // ---- rare fallback: refine prefix until candidate set fits in LDS.
  // Terminates: the last pass pins the full 48-bit key -> Sge == kK.
  while (Sge > kCap) {
    int w = (shift > 8) ? 8 : shift;
    int ns = shift - w;
    int bins = 1 << w;
    int hs = shift;                        // bits above [ns..ns+w) match prefix
    for (int i = tid; i < bins; i += 256) hist[i] = 0;
    __syncthreads();
    for (int i = tid; i < kN4; i += 256) {
      float4 f = s4[i];
      int n = i * 4;
      float sv[4] = {f.x, f.y, f.z, f.w};
      for (int j = 0; j < 4; ++j) {
        uint64_t k = make_key(sv[j], n + j);
        if ((k >> hs) == prefix)
          atomicAdd(&hist[(uint32_t)(k >> ns) & (bins - 1)], 1u);
      }
    }
    __syncthreads();
    uint32_t v = (tid < bins) ? hist[bins - 1 - tid] : 0;
    uint32_t S = block_scan_incl(v);
    if (v && S >= krem && (S - v) < krem) {
      sel_bin = bins - 1 - tid; sel_hd = v; sel_above = S - v;
    }
    __syncthreads();
    prefix = (prefix << w) | (uint32_t)sel_bin;
    krem -= sel_above;
    Sge = (kK - krem) + sel_hd;
    shift = ns;
    __syncthreads();
  }

  // ---- pass 2: gather all keys >= L into LDS (exactly Sge of them) ----
  uint64_t L = prefix << shift;
  if (tid == 0) cnt = 0;
  __syncthreads();
  {
    int lane = tid & 63;
    for (int i = tid; i < kN4; i += 256) {
      float4 f = s4[i];
      int n = i * 4;
      float sv[4] = {f.x, f.y, f.z, f.w};
      for (int j = 0; j < 4; ++j) {
        uint64_t k = make_key(sv[j], n + j);
        bool pred = (k >= L);
        unsigned long long m = __ballot(pred);
        if (m) {
          uint32_t bcast = 0;
          if (lane == 0) bcast = atomicAdd(&cnt, (uint32_t)__popcll(m));
          bcast = (uint32_t)__shfl((int)bcast, 0);
          if (pred) {
            uint32_t pos = bcast + (uint32_t)__popcll(m & ((1ull << lane) - 1ull));
            if (pos < kCap) keybuf[pos] = k;
          }
        }
      }
    }
  }
  __syncthreads();
  int Scnt = (int)cnt;
  if (Scnt > kCap) Scnt = kCap;            // safety (cannot happen by construction)

  // ---- in-LDS select+sort: rank-count each candidate; rank<256 -> slot ----
  for (int j = tid; j < Scnt; j += 256) {
    uint64_t kj = keybuf[j];
    int r = 0;
    for (int i = 0; i < Scnt; ++i) r += (keybuf[i] > kj);
    if (r < kK) skey[r] = kj;
  }
  __syncthreads();

  // ---- load candidate boxes, greedy NMS (exact reference op order) ----
  __shared__ float by1[kK], bx1[kK], by2[kK], bx2[kK], barea[kK], bsc[kK];
  __shared__ int keep[kK];
  uint64_t myk = skey[tid];
  int n = 0xFFFF - (int)(myk & 0xFFFF);
  float sc_v = __uint_as_float((uint32_t)(myk >> 16));
  const float4 bb = ((const float4*)boxes)[(size_t)b * kN + n];
  by1[tid] = bb.x; bx1[tid] = bb.y; by2[tid] = bb.z; bx2[tid] = bb.w;
  barea[tid] = (bb.z - bb.x) * (bb.w - bb.y);
  bsc[tid] = sc_v;
  keep[tid] = (sc_v > 0.05f) ? 1 : 0;      // valid = top_s > CONF_THR
  __syncthreads();

  float my_y1 = bb.x, my_x1 = bb.y, my_y2 = bb.z, my_x2 = bb.w;
  float my_a = barea[tid];
  for (int i = 0; i < kK; ++i) {
    if (keep[i]) {                         // uniform across block
      if (tid > i && keep[tid]) {
        float yy1 = fmaxf(by1[i], my_y1);
        float yy2 = fminf(by2[i], my_y2);
        float xx1 = fmaxf(bx1[i], my_x1);
        float xx2 = fminf(bx2[i], my_x2);
        float ih = fmaxf(yy2 - yy1, 0.0f);
        float iw = fmaxf(xx2 - xx1, 0.0f);
        float inter = ih * iw;
        float un = barea[i] + my_a - inter;
        float iou = inter / fmaxf(un, 1e-8f);
        if (iou > 0.5f) keep[tid] = 0;
      }
    }
    __syncthreads();
  }

  // ---- stable top-100 of kept scores (zeros tie-break by position) ----
  float ks = keep[tid] ? bsc[tid] : 0.0f;
  uint64_t k2 = ((uint64_t)__float_as_uint(ks) << 16) | (uint32_t)(0xFFFF - tid);
  skey[tid] = k2;
  __syncthreads();
  int rank2 = 0;
  for (int i = 0; i < kK; ++i) rank2 += (skey[i] > k2);
  if (rank2 < kMaxPC) {
    size_t obase = ((size_t)(b * kC + c)) * kMaxPC + rank2;
    cls_scores[obase] = ks;
    float* ob = cls_boxes + obase * 4;
    ob[0] = my_y1; ob[1] = my_x1; ob[2] = my_y2; ob[3] = my_x2;
  }
}

// ---- per-batch: stable top-100 over 80*100 entries, write final outputs ----
__global__ __launch_bounds__(256) void final_topk_kernel(
    const float* __restrict__ cls_scores, const float* __restrict__ cls_boxes,
    float* __restrict__ out) {
  int b = blockIdx.x;
  int tid = threadIdx.x;
  const int M = kC * kMaxPC;  // 8000
  const float* s = cls_scores + (size_t)b * M;

  uint64_t thr = radix_select(s, M, kMaxDet);

  __shared__ uint32_t cnt;
  __shared__ uint64_t gkey[kMaxDet];
  if (tid == 0) cnt = 0;
  __syncthreads();
  for (int f = tid; f < M; f += 256) {
    uint64_t k = make_key(s[f], f);
    if (k >= thr) gkey[atomicAdd(&cnt, 1u)] = k;
  }
  __syncthreads();

  if (tid < kMaxDet) {
    uint64_t myk = gkey[tid];
    int rank = 0;
    for (int i = 0; i < kMaxDet; ++i) rank += (gkey[i] > myk);
    float sv = __uint_as_float((uint32_t)(myk >> 16));
    int f = 0xFFFF - (int)(myk & 0xFFFF);
    int cls = f / 100;
    const float* bp = cls_boxes + ((size_t)b * M + f) * 4;
    float m = (sv > 0.0f) ? 1.0f : 0.0f;   // fin_b zeroed where fin_s <= 0
    float* ob = out + ((size_t)b * kMaxDet + rank) * 4;
    ob[0] = bp[0] * m; ob[1] = bp[1] * m; ob[2] = bp[2] * m; ob[3] = bp[3] * m;
    out[(size_t)kB * kMaxDet * 4 + (size_t)b * kMaxDet + rank] = (float)cls;
    out[(size_t)kB * kMaxDet * 5 + (size_t)b * kMaxDet + rank] = sv;
  }
}

extern "C" void kernel_launch(void* const* d_in, const int* in_sizes, int n_in,
                              void* d_out, int out_size, void* d_ws, size_t ws_size,
                              hipStream_t stream) {
  (void)in_sizes; (void)n_in; (void)out_size;
  const float* regs = (const float*)d_in[0];
  const float* ctrs = (const float*)d_in[1];
  const float* clfs = (const float*)d_in[2];
  float* out = (float*)d_out;

  const size_t boxesB  = (size_t)kB * kN * 4 * sizeof(float);          // 5.6 MB
  const size_t clsBoxB = (size_t)kB * kC * kMaxPC * 4 * sizeof(float); // 2.0 MB
  const size_t clsScB  = (size_t)kB * kC * kMaxPC * sizeof(float);     // 0.5 MB
  const size_t fixed = boxesB + clsBoxB + clsScB;

  // scores_t needs cb*80*N*4 bytes; chunk batches if ws is small.
  int cb = 0;
  for (int t : {16, 8, 4, 2, 1}) {
    if (ws_size >= fixed + (size_t)t * kC * kN * sizeof(float)) { cb = t; break; }
  }
  if (cb == 0) return;  // workspace too small -- fail visibly, no OOB writes

  char* p = (char*)d_ws;
  float* boxes      = (float*)p; p += boxesB;
  float* cls_boxes  = (float*)p; p += clsBoxB;
  float* cls_scores = (float*)p; p += clsScB;
  float* scores_t   = (float*)p;

  decode_boxes_kernel<<<(kB * kN + 255) / 256, 256, 0, stream>>>(regs, boxes);
  for (int b0 = 0; b0 < kB; b0 += cb) {
    score_transpose_kernel<<<dim3(kN / 32, cb), 256, 0, stream>>>(clfs, ctrs, scores_t, b0);
    nms_class_kernel<<<cb * kC, 256, 0, stream>>>(scores_t, boxes, cls_boxes, cls_scores, b0);
  }
  final_topk_kernel<<<kB, 256, 0, stream>>>(cls_scores, cls_boxes, out);
}

// Round 3
// 361.449 us; speedup vs baseline: 1.5686x; 1.1705x over previous
//
#include <hip/hip_runtime.h>
#include <stdint.h>
#include <initializer_list>

// Keep every f32 op un-fused: the reference (numpy/jax f32) computes
// inter = ih*iw; union = a_i + a_j - inter as separate rounded ops. With
// HIP's default -ffp-contract=fast the subtract would fuse into an FMA and
// could flip borderline iou > 0.5 decisions -> wrong box selected.
#pragma clang fp contract(off)

namespace {
constexpr int kN = 21824;      // 128^2 + 64^2 + 32^2 + 16^2 + 8^2
constexpr int kB = 16;
constexpr int kC = 80;
constexpr int kK = 256;        // K_CAND
constexpr int kMaxPC = 100;
constexpr int kMaxDet = 100;
constexpr int kBins1 = 2048;   // first-pass histogram bins (top 11 score bits)
constexpr int kCap = 1536;     // LDS candidate capacity (u64 keys)
}

// ---- 48-bit sort key: score bits (high 32) | (0xFFFF - index) (low 16) ----
// scores are >= 0 so the raw f32 bit pattern is order-monotone; the index
// complement reproduces jax top_k's stable tie-break (lower index wins).
__device__ __forceinline__ uint64_t make_key(float s, int n) {
  return ((uint64_t)__float_as_uint(s) << 16) | (uint32_t)(0xFFFF - n);
}

// Block-wide (256 threads) inclusive prefix scan.
__device__ uint32_t block_scan_incl(uint32_t val) {
  __shared__ uint32_t wsum[4];
  int lane = threadIdx.x & 63;
  int wave = threadIdx.x >> 6;
  for (int d = 1; d < 64; d <<= 1) {
    uint32_t t = __shfl_up(val, (unsigned)d, 64);
    if (lane >= d) val += t;
  }
  if (lane == 63) wsum[wave] = val;
  __syncthreads();
  uint32_t off = 0;
  for (int w = 0; w < wave; ++w) off += wsum[w];
  __syncthreads();
  return val + off;
}

// Exact top-K threshold over count global floats (final top-100 over 8000
// only): returns the full 48-bit key of the K-th largest.
__device__ uint64_t radix_select(const float* __restrict__ s, int count, int K) {
  __shared__ uint32_t hist[256];
  __shared__ int sel_d;
  __shared__ uint32_t sel_k;
  int tid = threadIdx.x;
  uint64_t prefix = 0;
  uint32_t krem = (uint32_t)K;
  for (int shift = 40; shift >= 0; shift -= 8) {
    hist[tid] = 0;
    __syncthreads();
    uint64_t pmask = (shift == 40) ? 0ull : (~0ull << (shift + 8));
    for (int n = tid; n < count; n += 256) {
      uint64_t k = make_key(s[n], n);
      if ((k & pmask) == prefix)
        atomicAdd(&hist[(uint32_t)(k >> shift) & 0xFFu], 1u);
    }
    __syncthreads();
    uint32_t v = hist[255 - tid];
    uint32_t S = block_scan_incl(v);
    if (S >= krem && (S - v) < krem) {
      sel_d = 255 - tid;
      sel_k = krem - (S - v);
    }
    __syncthreads();
    prefix |= ((uint64_t)sel_d) << shift;
    krem = sel_k;
    __syncthreads();
  }
  return prefix;
}

// ---- fused score (clf*ctr) + transpose (b,N,C) -> (lb,C,N) ----
__global__ __launch_bounds__(256) void score_transpose_kernel(
    const float* __restrict__ clfs, const float* __restrict__ ctrs,
    float* __restrict__ scores_t, int b0) {
  __shared__ float tile[32][81];   // +1 pad: conflict-free column reads
  __shared__ float ctile[32];
  int lb = blockIdx.y;             // local batch within chunk
  int b = lb + b0;
  int n0 = blockIdx.x * 32;
  int tid = threadIdx.x;
  if (tid < 32) ctile[tid] = ctrs[(size_t)b * kN + n0 + tid];
  const float4* src = (const float4*)(clfs + ((size_t)b * kN + n0) * kC);
  for (int e = tid; e < 32 * kC / 4; e += 256) {
    float4 v = src[e];
    int base = e * 4;
    tile[base / kC][base % kC] = v.x;       // kC=80: elements of one float4
    tile[(base + 1) / kC][(base + 1) % kC] = v.y;
    tile[(base + 2) / kC][(base + 2) % kC] = v.z;
    tile[(base + 3) / kC][(base + 3) % kC] = v.w;
  }
  __syncthreads();
  for (int e = tid; e < 32 * kC; e += 256) {
    int c = e >> 5;
    int nl = e & 31;
    scores_t[((size_t)(lb * kC + c)) * kN + n0 + nl] = tile[nl][c] * ctile[nl];
  }
}

// ---- per-(batch,class): 2-pass exact top-256 -> greedy NMS -> top-100 ----
__global__ __launch_bounds__(256) void nms_class_kernel(
    const float* __restrict__ scores_t, const float* __restrict__ regs,
    float* __restrict__ cls_boxes, float* __restrict__ cls_scores, int b0) {
  int lb = blockIdx.x / kC;
  int c = blockIdx.x % kC;
  int b = lb + b0;
  int tid = threadIdx.x;
  const float* s = scores_t + ((size_t)(lb * kC + c)) * kN;
  const float4* s4 = (const float4*)s;     // rows are 16B-aligned
  constexpr int kN4 = kN / 4;              // 5456, exact

  __shared__ uint32_t hist[kBins1];        // 8 KB
  __shared__ uint64_t keybuf[kCap];        // 12 KB
  __shared__ uint64_t cbuf[kK];            // 2 KB, exact top-256 (unsorted)
  __shared__ uint64_t skey[kK];            // 2 KB, sorted top-256 keys
  __shared__ int sel_bin;
  __shared__ uint32_t sel_hd, sel_above, sel_k;
  __shared__ uint32_t cnt;

  // ---- pass 1: 2048-bin histogram over score bits >> 21 ----
  for (int i = tid; i < kBins1; i += 256) hist[i] = 0;
  __syncthreads();
  for (int i = tid; i < kN4; i += 256) {
    float4 f = s4[i];
    atomicAdd(&hist[__float_as_uint(f.x) >> 21], 1u);
    atomicAdd(&hist[__float_as_uint(f.y) >> 21], 1u);
    atomicAdd(&hist[__float_as_uint(f.z) >> 21], 1u);
    atomicAdd(&hist[__float_as_uint(f.w) >> 21], 1u);
  }
  __syncthreads();
  // descending scan: thread t covers bins [2047-8t .. 2040-8t]
  uint32_t krem = kK;
  {
    uint32_t bl[8], v = 0;
    int base = kBins1 - 1 - 8 * tid;
    for (int j = 0; j < 8; ++j) { bl[j] = hist[base - j]; v += bl[j]; }
    uint32_t S = block_scan_incl(v);
    if (S >= krem && (S - v) < krem) {
      uint32_t cum = S - v;
      for (int j = 0; j < 8; ++j) {
        cum += bl[j];
        if (cum >= krem) { sel_bin = base - j; sel_hd = bl[j]; sel_above = cum - bl[j]; break; }
      }
    }
    __syncthreads();
  }
  uint64_t prefix = (uint64_t)sel_bin;
  krem = kK - sel_above;
  uint32_t Sge = (kK - krem) + sel_hd;     // candidate count at this floor
  int shift = 37;
  __syncthreads();

  // ---- rare fallback: refine prefix until candidate set fits in LDS ----
  while (Sge > kCap) {
    int w = (shift > 8) ? 8 : shift;
    int ns = shift - w;
    int bins = 1 << w;
    int hs = shift;
    for (int i = tid; i < bins; i += 256) hist[i] = 0;
    __syncthreads();
    for (int i = tid; i < kN4; i += 256) {
      float4 f = s4[i];
      int n = i * 4;
      float sv[4] = {f.x, f.y, f.z, f.w};
      for (int j = 0; j < 4; ++j) {
        uint64_t k = make_key(sv[j], n + j);
        if ((k >> hs) == prefix)
          atomicAdd(&hist[(uint32_t)(k >> ns) & (bins - 1)], 1u);
      }
    }
    __syncthreads();
    uint32_t v = (tid < bins) ? hist[bins - 1 - tid] : 0;
    uint32_t S = block_scan_incl(v);
    if (v && S >= krem && (S - v) < krem) {
      sel_bin = bins - 1 - tid; sel_hd = v; sel_above = S - v;
    }
    __syncthreads();
    prefix = (prefix << w) | (uint32_t)sel_bin;
    krem -= sel_above;
    Sge = (kK - krem) + sel_hd;
    shift = ns;
    __syncthreads();
  }

  // ---- pass 2: gather all keys >= L into LDS (exactly Sge of them) ----
  uint64_t L = prefix << shift;
  if (tid == 0) cnt = 0;
  __syncthreads();
  {
    int lane = tid & 63;
    for (int i = tid; i < kN4; i += 256) {
      float4 f = s4[i];
      int n = i * 4;
      float sv[4] = {f.x, f.y, f.z, f.w};
      for (int j = 0; j < 4; ++j) {
        uint64_t k = make_key(sv[j], n + j);
        bool pred = (k >= L);
        unsigned long long m = __ballot(pred);
        if (m) {
          uint32_t bcast = 0;
          if (lane == 0) bcast = atomicAdd(&cnt, (uint32_t)__popcll(m));
          bcast = (uint32_t)__shfl((int)bcast, 0);
          if (pred) {
            uint32_t pos = bcast + (uint32_t)__popcll(m & ((1ull << lane) - 1ull));
            if (pos < kCap) keybuf[pos] = k;
          }
        }
      }
    }
  }
  __syncthreads();
  int Scnt = (int)cnt;
  if (Scnt > kCap) Scnt = kCap;            // safety (cannot happen by construction)

  // ---- in-LDS exact radix select: 48-bit key of the 256th largest ----
  uint64_t thr48 = 0;
  uint32_t krem2 = kK;
  for (int sh = 40; sh >= 0; sh -= 8) {
    if (tid < 256) hist[tid] = 0;
    __syncthreads();
    uint64_t pmask = (sh == 40) ? 0ull : (~0ull << (sh + 8));
    for (int i = tid; i < Scnt; i += 256) {
      uint64_t k = keybuf[i];
      if ((k & pmask) == thr48)
        atomicAdd(&hist[(uint32_t)(k >> sh) & 0xFFu], 1u);
    }
    __syncthreads();
    uint32_t v = hist[255 - tid];
    uint32_t S = block_scan_incl(v);
    if (S >= krem2 && (S - v) < krem2) {
      sel_bin = 255 - tid;
      sel_k = krem2 - (S - v);
    }
    __syncthreads();
    thr48 |= ((uint64_t)sel_bin) << sh;
    krem2 = sel_k;
    __syncthreads();
  }

  // ---- compact the exact 256 qualifiers, then rank-sort (256-long loop) ----
  if (tid == 0) cnt = 0;
  __syncthreads();
  for (int i = tid; i < Scnt; i += 256) {
    uint64_t k = keybuf[i];
    if (k >= thr48) {
      uint32_t p = atomicAdd(&cnt, 1u);
      if (p < kK) cbuf[p] = k;             // exactly kK land here (keys unique)
    }
  }
  __syncthreads();
  uint64_t myk = cbuf[tid];
  {
    int r = 0;
    for (int i = 0; i < kK; ++i) r += (cbuf[i] > myk);
    skey[r] = myk;
  }
  __syncthreads();

  // ---- decode my candidate's box directly from regs (fused decode) ----
  __shared__ float by1[kK], bx1[kK], by2[kK], bx2[kK], barea[kK], bsc[kK];
  __shared__ int keep[kK];
  myk = skey[tid];
  int n = 0xFFFF - (int)(myk & 0xFFFF);
  float sc_v = __uint_as_float((uint32_t)(myk >> 16));
  int off, hl;
  float sf;
  if (n < 16384)      { off = 0;     hl = 7; sf = 8.f;   }
  else if (n < 20480) { off = 16384; hl = 6; sf = 16.f;  }
  else if (n < 21504) { off = 20480; hl = 5; sf = 32.f;  }
  else if (n < 21760) { off = 21504; hl = 4; sf = 64.f;  }
  else                { off = 21760; hl = 3; sf = 128.f; }
  int kk = n - off;
  // meshgrid(h, w) with 'xy' indexing -> gy = k % H, gx = k / H
  float gx = (float)(kk >> hl);
  float gy = (float)(kk & ((1 << hl) - 1));
  const float4 r = ((const float4*)regs)[(size_t)b * kN + n];
  float my_y1 = (gy - r.z) * sf;
  float my_x1 = (gx - r.x) * sf;
  float my_y2 = (gy + r.w) * sf;
  float my_x2 = (gx + r.y) * sf;
  float my_a = (my_y2 - my_y1) * (my_x2 - my_x1);
  by1[tid] = my_y1; bx1[tid] = my_x1; by2[tid] = my_y2; bx2[tid] = my_x2;
  barea[tid] = my_a;
  bsc[tid] = sc_v;
  keep[tid] = (sc_v > 0.05f) ? 1 : 0;      // valid = top_s > CONF_THR
  __syncthreads();

  // ---- greedy NMS (exact reference op order; contract(off) active) ----
  for (int i = 0; i < kK; ++i) {
    if (keep[i]) {                         // uniform across block
      if (tid > i && keep[tid]) {
        float yy1 = fmaxf(by1[i], my_y1);
        float yy2 = fminf(by2[i], my_y2);
        float xx1 = fmaxf(bx1[i], my_x1);
        float xx2 = fminf(bx2[i], my_x2);
        float ih = fmaxf(yy2 - yy1, 0.0f);
        float iw = fmaxf(xx2 - xx1, 0.0f);
        float inter = ih * iw;
        float un = barea[i] + my_a - inter;
        float iou = inter / fmaxf(un, 1e-8f);
        if (iou > 0.5f) keep[tid] = 0;
      }
    }
    __syncthreads();
  }

  // ---- stable top-100 of kept scores via ballot prefix ----
  // Kept candidates are already in descending (score, -index) order; zero
  // slots tie-break by position. So final order = kept (tid order) then
  // suppressed (tid order) -- identical to the reference's stable top_k.
  __shared__ uint32_t wkc[4];
  bool keptf = keep[tid] != 0;
  unsigned long long km = __ballot(keptf);
  int lane = tid & 63, wave = tid >> 6;
  if (lane == 0) wkc[wave] = (uint32_t)__popcll(km);
  __syncthreads();
  int kept_before = (int)__popcll(km & ((1ull << (unsigned)lane) - 1ull));
  for (int w = 0; w < wave; ++w) kept_before += (int)wkc[w];
  int kept_total = (int)(wkc[0] + wkc[1] + wkc[2] + wkc[3]);
  int rank2 = keptf ? kept_before : (kept_total + tid - kept_before);
  if (rank2 < kMaxPC) {
    float ks = keptf ? sc_v : 0.0f;
    size_t obase = ((size_t)(b * kC + c)) * kMaxPC + rank2;
    cls_scores[obase] = ks;
    float* ob = cls_boxes + obase * 4;
    ob[0] = my_y1; ob[1] = my_x1; ob[2] = my_y2; ob[3] = my_x2;
  }
}

// ---- per-batch: stable top-100 over 80*100 entries, write final outputs ----
__global__ __launch_bounds__(256) void final_topk_kernel(
    const float* __restrict__ cls_scores, const float* __restrict__ cls_boxes,
    float* __restrict__ out) {
  int b = blockIdx.x;
  int tid = threadIdx.x;
  const int M = kC * kMaxPC;  // 8000
  const float* s = cls_scores + (size_t)b * M;

  uint64_t thr = radix_select(s, M, kMaxDet);

  __shared__ uint32_t cnt;
  __shared__ uint64_t gkey[kMaxDet];
  if (tid == 0) cnt = 0;
  __syncthreads();
  for (int f = tid; f < M; f += 256) {
    uint64_t k = make_key(s[f], f);
    if (k >= thr) gkey[atomicAdd(&cnt, 1u)] = k;
  }
  __syncthreads();

  if (tid < kMaxDet) {
    uint64_t myk = gkey[tid];
    int rank = 0;
    for (int i = 0; i < kMaxDet; ++i) rank += (gkey[i] > myk);
    float sv = __uint_as_float((uint32_t)(myk >> 16));
    int f = 0xFFFF - (int)(myk & 0xFFFF);
    int cls = f / 100;
    const float* bp = cls_boxes + ((size_t)b * M + f) * 4;
    float m = (sv > 0.0f) ? 1.0f : 0.0f;   // fin_b zeroed where fin_s <= 0
    float* ob = out + ((size_t)b * kMaxDet + rank) * 4;
    ob[0] = bp[0] * m; ob[1] = bp[1] * m; ob[2] = bp[2] * m; ob[3] = bp[3] * m;
    out[(size_t)kB * kMaxDet * 4 + (size_t)b * kMaxDet + rank] = (float)cls;
    out[(size_t)kB * kMaxDet * 5 + (size_t)b * kMaxDet + rank] = sv;
  }
}

extern "C" void kernel_launch(void* const* d_in, const int* in_sizes, int n_in,
                              void* d_out, int out_size, void* d_ws, size_t ws_size,
                              hipStream_t stream) {
  (void)in_sizes; (void)n_in; (void)out_size;
  const float* regs = (const float*)d_in[0];
  const float* ctrs = (const float*)d_in[1];
  const float* clfs = (const float*)d_in[2];
  float* out = (float*)d_out;

  const size_t clsBoxB = (size_t)kB * kC * kMaxPC * 4 * sizeof(float); // 2.0 MB
  const size_t clsScB  = (size_t)kB * kC * kMaxPC * sizeof(float);     // 0.5 MB
  const size_t fixed = clsBoxB + clsScB;

  // scores_t needs cb*80*N*4 bytes; chunk batches if ws is small.
  int cb = 0;
  for (int t : {16, 8, 4, 2, 1}) {
    if (ws_size >= fixed + (size_t)t * kC * kN * sizeof(float)) { cb = t; break; }
  }
  if (cb == 0) return;  // workspace too small -- fail visibly, no OOB writes

  char* p = (char*)d_ws;
  float* cls_boxes  = (float*)p; p += clsBoxB;
  float* cls_scores = (float*)p; p += clsScB;
  float* scores_t   = (float*)p;

  for (int b0 = 0; b0 < kB; b0 += cb) {
    score_transpose_kernel<<<dim3(kN / 32, cb), 256, 0, stream>>>(clfs, ctrs, scores_t, b0);
    nms_class_kernel<<<cb * kC, 256, 0, stream>>>(scores_t, regs, cls_boxes, cls_scores, b0);
  }
  final_topk_kernel<<<kB, 256, 0, stream>>>(cls_scores, cls_boxes, out);
}

// Round 4
// 337.337 us; speedup vs baseline: 1.6807x; 1.0715x over previous
//
#include <hip/hip_runtime.h>
#include <stdint.h>
#include <initializer_list>

// Keep every f32 op un-fused: the reference (numpy/jax f32) computes
// inter = ih*iw; union = a_i + a_j - inter as separate rounded ops. With
// HIP's default -ffp-contract=fast the subtract would fuse into an FMA and
// could flip borderline iou > 0.5 decisions -> wrong box selected.
#pragma clang fp contract(off)

namespace {
constexpr int kN = 21824;      // 128^2 + 64^2 + 32^2 + 16^2 + 8^2
constexpr int kB = 16;
constexpr int kC = 80;
constexpr int kK = 256;        // K_CAND
constexpr int kMaxPC = 100;
constexpr int kMaxDet = 100;
constexpr int kBins1 = 2048;   // first-pass histogram bins (top 11 score bits)
constexpr int kCap = 1536;     // LDS candidate capacity (u64 keys)
// Exact iou>0.5 without division: RN(inter/unc) > 0.5  <=>  inter > (0.5+2^-25)*unc.
// (0.5+2^-25)*unc is exact in double (25b x 24b mantissa <= 49b); the tie at
// q = 0.5+2^-25 rounds-to-even down to 0.5, so the strict > matches exactly.
constexpr double kIouC = 0x1.000001p-1;   // 0.5 + 2^-25
}

// ---- 48-bit sort key: score bits (high 32) | (0xFFFF - index) (low 16) ----
// scores are >= 0 so the raw f32 bit pattern is order-monotone; the index
// complement reproduces jax top_k's stable tie-break (lower index wins).
__device__ __forceinline__ uint64_t make_key(float s, int n) {
  return ((uint64_t)__float_as_uint(s) << 16) | (uint32_t)(0xFFFF - n);
}

// Block-wide (256 threads) inclusive prefix scan.
__device__ uint32_t block_scan_incl(uint32_t val) {
  __shared__ uint32_t wsum[4];
  int lane = threadIdx.x & 63;
  int wave = threadIdx.x >> 6;
  for (int d = 1; d < 64; d <<= 1) {
    uint32_t t = __shfl_up(val, (unsigned)d, 64);
    if (lane >= d) val += t;
  }
  if (lane == 63) wsum[wave] = val;
  __syncthreads();
  uint32_t off = 0;
  for (int w = 0; w < wave; ++w) off += wsum[w];
  __syncthreads();
  return val + off;
}

// ---- 2-pass exact top-K: 2048-bin histogram -> gather >= floor into LDS ->
// in-LDS exact radix select -> compact exactly K keys (unsorted) into cbuf.
// Rare fallback refines the floor until the candidate set fits in kCap.
__device__ void select_topk(const float4* __restrict__ s4, int n4, int K,
                            uint32_t* hist, uint64_t* keybuf, uint64_t* cbuf) {
  __shared__ int sel_bin;
  __shared__ uint32_t sel_hd, sel_above, sel_k, cnt;
  int tid = threadIdx.x;

  // pass 1: 2048-bin histogram over score bits >> 21 (= key bits [37..48))
  for (int i = tid; i < kBins1; i += 256) hist[i] = 0;
  __syncthreads();
  for (int i = tid; i < n4; i += 256) {
    float4 f = s4[i];
    atomicAdd(&hist[__float_as_uint(f.x) >> 21], 1u);
    atomicAdd(&hist[__float_as_uint(f.y) >> 21], 1u);
    atomicAdd(&hist[__float_as_uint(f.z) >> 21], 1u);
    atomicAdd(&hist[__float_as_uint(f.w) >> 21], 1u);
  }
  __syncthreads();
  uint32_t krem = (uint32_t)K;
  {
    uint32_t bl[8], v = 0;
    int base = kBins1 - 1 - 8 * tid;
    for (int j = 0; j < 8; ++j) { bl[j] = hist[base - j]; v += bl[j]; }
    uint32_t S = block_scan_incl(v);
    if (S >= krem && (S - v) < krem) {
      uint32_t cum = S - v;
      for (int j = 0; j < 8; ++j) {
        cum += bl[j];
        if (cum >= krem) { sel_bin = base - j; sel_hd = bl[j]; sel_above = cum - bl[j]; break; }
      }
    }
    __syncthreads();
  }
  uint64_t prefix = (uint64_t)sel_bin;
  krem = (uint32_t)K - sel_above;
  uint32_t Sge = ((uint32_t)K - krem) + sel_hd;
  int shift = 37;
  __syncthreads();

  // rare fallback: refine prefix until candidate set fits in LDS
  while (Sge > kCap) {
    int w = (shift > 8) ? 8 : shift;
    int ns = shift - w;
    int bins = 1 << w;
    int hs = shift;
    for (int i = tid; i < bins; i += 256) hist[i] = 0;
    __syncthreads();
    for (int i = tid; i < n4; i += 256) {
      float4 f = s4[i];
      int n = i * 4;
      float sv[4] = {f.x, f.y, f.z, f.w};
      for (int j = 0; j < 4; ++j) {
        uint64_t k = make_key(sv[j], n + j);
        if ((k >> hs) == prefix)
          atomicAdd(&hist[(uint32_t)(k >> ns) & (bins - 1)], 1u);
      }
    }
    __syncthreads();
    uint32_t v = (tid < bins) ? hist[bins - 1 - tid] : 0;
    uint32_t S = block_scan_incl(v);
    if (v && S >= krem && (S - v) < krem) {
      sel_bin = bins - 1 - tid; sel_hd = v; sel_above = S - v;
    }
    __syncthreads();
    prefix = (prefix << w) | (uint32_t)sel_bin;
    krem -= sel_above;
    Sge = ((uint32_t)K - krem) + sel_hd;
    shift = ns;
    __syncthreads();
  }

  // pass 2: gather all keys >= floor into LDS (exactly Sge of them)
  uint64_t L = prefix << shift;
  if (tid == 0) cnt = 0;
  __syncthreads();
  {
    int lane = tid & 63;
    for (int i = tid; i < n4; i += 256) {
      float4 f = s4[i];
      int n = i * 4;
      float sv[4] = {f.x, f.y, f.z, f.w};
      for (int j = 0; j < 4; ++j) {
        uint64_t k = make_key(sv[j], n + j);
        bool pred = (k >= L);
        unsigned long long m = __ballot(pred);
        if (m) {
          uint32_t bcast = 0;
          if (lane == 0) bcast = atomicAdd(&cnt, (uint32_t)__popcll(m));
          bcast = (uint32_t)__shfl((int)bcast, 0);
          if (pred) {
            uint32_t pos = bcast + (uint32_t)__popcll(m & ((1ull << lane) - 1ull));
            if (pos < kCap) keybuf[pos] = k;
          }
        }
      }
    }
  }
  __syncthreads();
  int Scnt = (int)cnt;
  if (Scnt > kCap) Scnt = kCap;            // safety (cannot happen by construction)

  // in-LDS exact radix select: 48-bit key of the K-th largest
  uint64_t thr48 = 0;
  uint32_t krem2 = (uint32_t)K;
  for (int sh = 40; sh >= 0; sh -= 8) {
    if (tid < 256) hist[tid] = 0;
    __syncthreads();
    uint64_t pmask = (sh == 40) ? 0ull : (~0ull << (sh + 8));
    for (int i = tid; i < Scnt; i += 256) {
      uint64_t k = keybuf[i];
      if ((k & pmask) == thr48)
        atomicAdd(&hist[(uint32_t)(k >> sh) & 0xFFu], 1u);
    }
    __syncthreads();
    uint32_t v = hist[255 - tid];
    uint32_t S = block_scan_incl(v);
    if (S >= krem2 && (S - v) < krem2) {
      sel_bin = 255 - tid;
      sel_k = krem2 - (S - v);
    }
    __syncthreads();
    thr48 |= ((uint64_t)sel_bin) << sh;
    krem2 = sel_k;
    __syncthreads();
  }

  // compact exactly K qualifiers (unsorted) into cbuf
  if (tid == 0) cnt = 0;
  __syncthreads();
  for (int i = tid; i < Scnt; i += 256) {
    uint64_t k = keybuf[i];
    if (k >= thr48) {
      uint32_t p = atomicAdd(&cnt, 1u);
      if (p < (uint32_t)K) cbuf[p] = k;
    }
  }
  __syncthreads();
}

// ---- fused score (clf*ctr) + transpose (b,N,C) -> (lb,C,N), float4 I/O ----
__global__ __launch_bounds__(256) void score_transpose_kernel(
    const float* __restrict__ clfs, const float* __restrict__ ctrs,
    float* __restrict__ scores_t, int b0) {
  __shared__ float tile[64][81];   // +1 pad: conflict-free column reads
  __shared__ float ct[64];
  int lb = blockIdx.y;             // local batch within chunk
  int b = lb + b0;
  int n0 = blockIdx.x * 64;        // kN = 64*341 exact
  int tid = threadIdx.x;
  if (tid < 64) ct[tid] = ctrs[(size_t)b * kN + n0 + tid];
  const float4* src = (const float4*)(clfs + ((size_t)b * kN + n0) * kC);
  #pragma unroll
  for (int e = tid; e < 64 * kC / 4; e += 256) {   // 1280 float4 loads
    float4 v = src[e];
    int base = e * 4;
    tile[base / kC][base % kC] = v.x;
    tile[(base + 1) / kC][(base + 1) % kC] = v.y;
    tile[(base + 2) / kC][(base + 2) % kC] = v.z;
    tile[(base + 3) / kC][(base + 3) % kC] = v.w;
  }
  __syncthreads();
  #pragma unroll
  for (int e = tid; e < 64 * kC / 4; e += 256) {   // 1280 float4 stores
    int c = e >> 4;
    int q = (e & 15) * 4;
    float4 o;
    o.x = tile[q][c] * ct[q];
    o.y = tile[q + 1][c] * ct[q + 1];
    o.z = tile[q + 2][c] * ct[q + 2];
    o.w = tile[q + 3][c] * ct[q + 3];
    *(float4*)&scores_t[((size_t)(lb * kC + c)) * kN + n0 + q] = o;
  }
}

// ---- per-(batch,class): top-256 -> bit-matrix NMS (barrier-free) -> top-100
__global__ __launch_bounds__(256) void nms_class_kernel(
    const float* __restrict__ scores_t, const float* __restrict__ regs,
    float* __restrict__ cls_boxes, float* __restrict__ cls_scores, int b0) {
  int lb = blockIdx.x / kC;
  int c = blockIdx.x % kC;
  int b = lb + b0;
  int tid = threadIdx.x;
  int lane = tid & 63, wave = tid >> 6;
  const float* s = scores_t + ((size_t)(lb * kC + c)) * kN;
  const float4* s4 = (const float4*)s;
  constexpr int kN4 = kN / 4;

  __shared__ union {
    uint32_t hist[kBins1];                 // select phase
    uint64_t supm[kK][4];                  // NMS suppression bit-matrix (8 KB)
  } hu;
  __shared__ uint64_t keybuf[kCap];        // 12 KB
  __shared__ uint64_t cbuf[kK];            // exact top-256 (unsorted)
  __shared__ uint64_t skey[kK];            // sorted top-256 keys
  __shared__ float by1[kK], bx1[kK], by2[kK], bx2[kK], barea[kK];
  __shared__ uint64_t kinit[4];            // initial keep mask (valid bits)

  select_topk(s4, kN4, kK, hu.hist, keybuf, cbuf);

  // rank-sort the 256 (keys unique -> rank is a permutation)
  uint64_t myk = cbuf[tid];
  {
    int r = 0;
    for (int i = 0; i < kK; ++i) r += (cbuf[i] > myk);
    skey[r] = myk;
  }
  __syncthreads();

  // decode my candidate's box directly from regs (fused decode)
  myk = skey[tid];
  int n = 0xFFFF - (int)(myk & 0xFFFF);
  float sc_v = __uint_as_float((uint32_t)(myk >> 16));
  int off, hl;
  float sf;
  if (n < 16384)      { off = 0;     hl = 7; sf = 8.f;   }
  else if (n < 20480) { off = 16384; hl = 6; sf = 16.f;  }
  else if (n < 21504) { off = 20480; hl = 5; sf = 32.f;  }
  else if (n < 21760) { off = 21504; hl = 4; sf = 64.f;  }
  else                { off = 21760; hl = 3; sf = 128.f; }
  int kk = n - off;
  // meshgrid(h, w) with 'xy' indexing -> gy = k % H, gx = k / H
  float gx = (float)(kk >> hl);
  float gy = (float)(kk & ((1 << hl) - 1));
  const float4 r = ((const float4*)regs)[(size_t)b * kN + n];
  float my_y1 = (gy - r.z) * sf;
  float my_x1 = (gx - r.x) * sf;
  float my_y2 = (gy + r.w) * sf;
  float my_x2 = (gx + r.y) * sf;
  float my_a = (my_y2 - my_y1) * (my_x2 - my_x1);
  by1[tid] = my_y1; bx1[tid] = my_x1; by2[tid] = my_y2; bx2[tid] = my_x2;
  barea[tid] = my_a;
  // initial keep = valid (top_s > CONF_THR), in rank order
  unsigned long long vm = __ballot(sc_v > 0.05f);
  if (lane == 0) kinit[wave] = vm;
  __syncthreads();   // SoA boxes + kinit visible; hu.hist no longer needed

  // phase A: suppression rows -- thread i computes bits over j > i.
  // Exact reference arithmetic: fmax/fmin symmetric; area_j+area_i commutes;
  // contract(off) keeps inter separate from the union subtract; the double
  // compare is exactly RN(inter/unc) > 0.5 (see kIouC note).
  for (int w = 0; w < 4; ++w) {
    uint64_t bits = 0;
    int j0 = w << 6;
    int js = (tid + 1 > j0) ? tid + 1 : j0;
    int j1 = j0 + 64;
    for (int j = js; j < j1; ++j) {
      float yy1 = fmaxf(by1[j], my_y1);
      float yy2 = fminf(by2[j], my_y2);
      float xx1 = fmaxf(bx1[j], my_x1);
      float xx2 = fminf(bx2[j], my_x2);
      float ih = fmaxf(yy2 - yy1, 0.0f);
      float iw = fmaxf(xx2 - xx1, 0.0f);
      float inter = ih * iw;
      float un = (barea[j] + my_a) - inter;
      float unc = fmaxf(un, 1e-8f);
      bits |= ((uint64_t)((double)inter > kIouC * (double)unc)) << (j - j0);
    }
    hu.supm[tid][w] = bits;
  }
  __syncthreads();

  // phase B: greedy resolution, redundantly per wave (no barriers).
  // keep mask distributed: lane w (w<4) holds 64-bit word w.
  uint64_t kw = (lane < 4) ? kinit[lane] : 0ull;
  for (int i = 0; i < kK; ++i) {
    uint64_t wsrc = __shfl(kw, i >> 6);
    if ((wsrc >> (i & 63)) & 1ull) {       // wave-uniform branch
      if (lane < 4) kw &= ~hu.supm[i][lane];
    }
  }
  uint32_t myp = (uint32_t)__popcll(kw);
  uint64_t ww = __shfl(kw, wave);          // final keep word for my tids
  bool keptf = (ww >> lane) & 1ull;
  int kept_total = (int)(__shfl(myp, 0) + __shfl(myp, 1) +
                         __shfl(myp, 2) + __shfl(myp, 3));
  int kept_before = (int)__popcll(ww & ((1ull << lane) - 1ull));
  for (int w = 0; w < wave; ++w) kept_before += (int)__shfl(myp, w);

  // stable top-100 of kept scores: kept candidates are already in descending
  // (score,-index) order; zero slots tie-break by position. Final order =
  // kept (tid order) then suppressed (tid order) == reference stable top_k.
  int rank2 = keptf ? kept_before : (kept_total + tid - kept_before);
  if (rank2 < kMaxPC) {
    float ks = keptf ? sc_v : 0.0f;
    size_t obase = ((size_t)(b * kC + c)) * kMaxPC + rank2;
    cls_scores[obase] = ks;
    float* ob = cls_boxes + obase * 4;
    ob[0] = my_y1; ob[1] = my_x1; ob[2] = my_y2; ob[3] = my_x2;
  }
}

// ---- per-batch: stable top-100 over 80*100 entries, write final outputs ----
__global__ __launch_bounds__(256) void final_topk_kernel(
    const float* __restrict__ cls_scores, const float* __restrict__ cls_boxes,
    float* __restrict__ out) {
  int b = blockIdx.x;
  int tid = threadIdx.x;
  const int M = kC * kMaxPC;  // 8000
  const float* s = cls_scores + (size_t)b * M;

  __shared__ uint32_t hist[kBins1];
  __shared__ uint64_t keybuf[kCap];
  __shared__ uint64_t cbuf[kMaxDet];
  select_topk((const float4*)s, M / 4, kMaxDet, hist, keybuf, cbuf);

  if (tid < kMaxDet) {
    uint64_t myk = cbuf[tid];
    int rank = 0;
    for (int i = 0; i < kMaxDet; ++i) rank += (cbuf[i] > myk);
    float sv = __uint_as_float((uint32_t)(myk >> 16));
    int f = 0xFFFF - (int)(myk & 0xFFFF);
    int cls = f / 100;
    const float* bp = cls_boxes + ((size_t)b * M + f) * 4;
    float m = (sv > 0.0f) ? 1.0f : 0.0f;   // fin_b zeroed where fin_s <= 0
    float* ob = out + ((size_t)b * kMaxDet + rank) * 4;
    ob[0] = bp[0] * m; ob[1] = bp[1] * m; ob[2] = bp[2] * m; ob[3] = bp[3] * m;
    out[(size_t)kB * kMaxDet * 4 + (size_t)b * kMaxDet + rank] = (float)cls;
    out[(size_t)kB * kMaxDet * 5 + (size_t)b * kMaxDet + rank] = sv;
  }
}

extern "C" void kernel_launch(void* const* d_in, const int* in_sizes, int n_in,
                              void* d_out, int out_size, void* d_ws, size_t ws_size,
                              hipStream_t stream) {
  (void)in_sizes; (void)n_in; (void)out_size;
  const float* regs = (const float*)d_in[0];
  const float* ctrs = (const float*)d_in[1];
  const float* clfs = (const float*)d_in[2];
  float* out = (float*)d_out;

  const size_t clsBoxB = (size_t)kB * kC * kMaxPC * 4 * sizeof(float); // 2.0 MB
  const size_t clsScB  = (size_t)kB * kC * kMaxPC * sizeof(float);     // 0.5 MB
  const size_t fixed = clsBoxB + clsScB;

  // scores_t needs cb*80*N*4 bytes; chunk batches if ws is small.
  int cb = 0;
  for (int t : {16, 8, 4, 2, 1}) {
    if (ws_size >= fixed + (size_t)t * kC * kN * sizeof(float)) { cb = t; break; }
  }
  if (cb == 0) return;  // workspace too small -- fail visibly, no OOB writes

  char* p = (char*)d_ws;
  float* cls_boxes  = (float*)p; p += clsBoxB;
  float* cls_scores = (float*)p; p += clsScB;
  float* scores_t   = (float*)p;

  for (int b0 = 0; b0 < kB; b0 += cb) {
    score_transpose_kernel<<<dim3(kN / 64, cb), 256, 0, stream>>>(clfs, ctrs, scores_t, b0);
    nms_class_kernel<<<cb * kC, 256, 0, stream>>>(scores_t, regs, cls_boxes, cls_scores, b0);
  }
  final_topk_kernel<<<kB, 256, 0, stream>>>(cls_scores, cls_boxes, out);
}